// Round 4
// baseline (12013.678 us; speedup 1.0000x reference)
//
#include <hip/hip_runtime.h>

typedef unsigned short ushort_t;
typedef unsigned int uint_t;
typedef __attribute__((ext_vector_type(8))) short short8;
typedef __attribute__((ext_vector_type(4))) float f32x4;

static constexpr int V = 32000, H = 512, HALFD = 256, LSEQ = 1024, BB = 64;
static constexpr int RCH = 8192;                 // rows per encoder chunk

__device__ __forceinline__ ushort_t f2bf(float f) {
    uint_t u = __float_as_uint(f);
    u = (u + 0x7FFFu + ((u >> 16) & 1u)) >> 16;
    return (ushort_t)u;
}
__device__ __forceinline__ float bf2f(ushort_t u) {
    return __uint_as_float(((uint_t)u) << 16);
}

// ---------------- weight transpose + fp32->bf16 convert: Wt[n][k] = bf16(W[k][n]) --
__global__ void transpose_cvt(const float* __restrict__ W, ushort_t* __restrict__ Wt,
                              int K, int N) {
    __shared__ float tile[32][33];
    int k0 = blockIdx.y * 32, n0 = blockIdx.x * 32;
    int tx = threadIdx.x & 31, ty = threadIdx.x >> 5;   // 256 threads: ty 0..7
    #pragma unroll
    for (int i = 0; i < 32; i += 8)
        tile[ty + i][tx] = W[(size_t)(k0 + ty + i) * N + n0 + tx];
    __syncthreads();
    #pragma unroll
    for (int i = 0; i < 32; i += 8)
        Wt[(size_t)(n0 + ty + i) * K + k0 + tx] = f2bf(tile[tx][ty + i]);
}

// ---------------- embedding gather (chunk): e bf16 --------------------------------
__global__ void gather_kernel(const int* __restrict__ seq, const float* __restrict__ embed,
                              ushort_t* __restrict__ ebf) {
    int row = blockIdx.x;
    int tok = seq[row];
    float4 v = ((const float4*)(embed + (size_t)tok * H))[threadIdx.x];
    ushort4 o;
    o.x = f2bf(v.x); o.y = f2bf(v.y); o.z = f2bf(v.z); o.w = f2bf(v.w);
    ((ushort4*)(ebf + (size_t)row * H))[threadIdx.x] = o;
}

// ---------------- bf16 MFMA GEMM:  C = f(A[MxK] @ Bt[NxK]^T + bias (+res)) --------
// MODE: 0 = plain, 1 = relu, 3 = +residual(bf16). Output bf16.
template <int MODE>
__global__ __launch_bounds__(256) void mfma_gemm(
        const ushort_t* __restrict__ A, const ushort_t* __restrict__ Bt,
        const float* __restrict__ bias, const ushort_t* __restrict__ res,
        ushort_t* __restrict__ Cout, int N, int K) {
    __shared__ __align__(16) ushort_t Al[128][40];   // pad 32->40 kills 8-way conflicts
    __shared__ __align__(16) ushort_t Bl[128][40];
    int t = threadIdx.x;
    int m0 = blockIdx.y * 128, n0 = blockIdx.x * 128;
    int lane = t & 63, wid = t >> 6;
    int wm = (wid & 1) * 64, wn = (wid >> 1) * 64;
    int lid = lane & 15, quad = lane >> 4;
    int srow = t >> 2, skq = (t & 3) * 8;            // staging: 4 threads/row, 8 bf16 each

    f32x4 acc[4][4];
    #pragma unroll
    for (int i = 0; i < 4; ++i)
        #pragma unroll
        for (int j = 0; j < 4; ++j)
            acc[i][j] = (f32x4){0.f, 0.f, 0.f, 0.f};

    for (int k0 = 0; k0 < K; k0 += 32) {
        short8 a0 = *(const short8*)(A + (size_t)(m0 + srow) * K + k0 + skq);
        short8 a1 = *(const short8*)(A + (size_t)(m0 + 64 + srow) * K + k0 + skq);
        short8 b0 = *(const short8*)(Bt + (size_t)(n0 + srow) * K + k0 + skq);
        short8 b1 = *(const short8*)(Bt + (size_t)(n0 + 64 + srow) * K + k0 + skq);
        __syncthreads();
        *(short8*)&Al[srow][skq]      = a0;
        *(short8*)&Al[64 + srow][skq] = a1;
        *(short8*)&Bl[srow][skq]      = b0;
        *(short8*)&Bl[64 + srow][skq] = b1;
        __syncthreads();
        short8 af[4], bfr[4];
        #pragma unroll
        for (int i = 0; i < 4; ++i)
            af[i] = *(const short8*)&Al[wm + i * 16 + lid][quad * 8];
        #pragma unroll
        for (int i = 0; i < 4; ++i)
            bfr[i] = *(const short8*)&Bl[wn + i * 16 + lid][quad * 8];
        #pragma unroll
        for (int mt = 0; mt < 4; ++mt)
            #pragma unroll
            for (int nt = 0; nt < 4; ++nt)
                acc[mt][nt] = __builtin_amdgcn_mfma_f32_16x16x32_bf16(
                    af[mt], bfr[nt], acc[mt][nt], 0, 0, 0);
    }
    // epilogue: C/D layout col=lane&15, row=quad*4+reg  [m89/m91-verified]
    #pragma unroll
    for (int mt = 0; mt < 4; ++mt) {
        #pragma unroll
        for (int nt = 0; nt < 4; ++nt) {
            #pragma unroll
            for (int rg = 0; rg < 4; ++rg) {
                int row = m0 + wm + mt * 16 + quad * 4 + rg;
                int col = n0 + wn + nt * 16 + lid;
                float v = acc[mt][nt][rg] + bias[col];
                if (MODE == 1) v = fmaxf(v, 0.f);
                if (MODE == 3) v += bf2f(res[(size_t)row * N + col]);
                Cout[(size_t)row * N + col] = f2bf(v);
            }
        }
    }
}

// ---------------- LayerNorm over H=512 (bf16 in-place), one wave per row ----------
__global__ void ln_kernel(ushort_t* X, const float* __restrict__ g,
                          const float* __restrict__ bta) {
    int row = blockIdx.x * 4 + (threadIdx.x >> 6);
    int lane = threadIdx.x & 63;
    ushort_t* xr = X + (size_t)row * H + lane * 8;
    short8 xv = *(short8*)xr;
    float x[8];
    #pragma unroll
    for (int j = 0; j < 8; ++j) x[j] = bf2f((ushort_t)xv[j]);
    float s = 0.f, ss = 0.f;
    #pragma unroll
    for (int j = 0; j < 8; ++j) { s += x[j]; ss += x[j] * x[j]; }
    #pragma unroll
    for (int d = 1; d < 64; d <<= 1) { s += __shfl_xor(s, d); ss += __shfl_xor(ss, d); }
    float mu = s * (1.f / 512.f);
    float var = ss * (1.f / 512.f) - mu * mu;
    float rstd = rsqrtf(var + 1e-5f);
    float4 g0 = *(const float4*)(g + lane * 8);
    float4 g1 = *(const float4*)(g + lane * 8 + 4);
    float4 b0 = *(const float4*)(bta + lane * 8);
    float4 b1 = *(const float4*)(bta + lane * 8 + 4);
    float gg[8] = {g0.x, g0.y, g0.z, g0.w, g1.x, g1.y, g1.z, g1.w};
    float bb[8] = {b0.x, b0.y, b0.z, b0.w, b1.x, b1.y, b1.z, b1.w};
    short8 o;
    #pragma unroll
    for (int j = 0; j < 8; ++j)
        o[j] = (short)f2bf((x[j] - mu) * rstd * gg[j] + bb[j]);
    *(short8*)xr = o;
}

// ---------------- beta[row] = sum(k^2) + 1e-6 (bf16 input), one wave per row ------
__global__ void beta_kernel(const ushort_t* __restrict__ k, float* __restrict__ beta) {
    int row = blockIdx.x * 4 + (threadIdx.x >> 6);
    int lane = threadIdx.x & 63;
    ushort4 a = *(const ushort4*)(k + (size_t)row * HALFD + lane * 4);
    float ax = bf2f(a.x), ay = bf2f(a.y), az = bf2f(a.z), aw = bf2f(a.w);
    float s = ax * ax + ay * ay + az * az + aw * aw;
    #pragma unroll
    for (int d = 1; d < 64; d <<= 1) s += __shfl_xor(s, d);
    if (lane == 0) beta[row] = s + 1e-6f;
}

// ---------------- sequential delta-rule scan --------------------------------------
// grid 256: blk = b*4 + mat*2 + half. 256 threads = 4 waves.
// Wave w owns global rows [half*128 + w*32, +32); lane: rowgroup rg=lane>>3
// (4 rows), chunk q=lane&7 (32 cols). M[128] = 4 rows x 32 cols in VGPRs.
// Each wave stages its OWN copy of the k row into private LDS (bf16, 512 B),
// register-pipelined 3 steps ahead -> NO per-step __syncthreads. kq LDS reads
// use a rotated-word swizzle -> conflict-free.
__global__ __launch_bounds__(256, 1) void scan_kernel(
        const ushort_t* __restrict__ ks, const ushort_t* __restrict__ ke,
        const float* __restrict__ beta_s, const float* __restrict__ beta_e,
        float* __restrict__ c) {
    int blk = blockIdx.x;
    int b = blk >> 2, mat = (blk >> 1) & 1, half = blk & 1;
    const ushort_t* Kp = (mat ? ke : ks) + (size_t)b * LSEQ * HALFD;
    const float* Bp = (mat ? beta_e : beta_s) + (size_t)b * LSEQ;
    int t = threadIdx.x;
    int lane = t & 63, w = t >> 6;
    int q = lane & 7, rg = lane >> 3;

    __shared__ uint_t kw[4][2][128];   // per-wave double-buffered k row (bf16 pairs)
    __shared__ float bets[LSEQ];       // all betas, staged once

    // stage betas block-wide (once)
    #pragma unroll
    for (int i = 0; i < 4; ++i) bets[t + i * 256] = Bp[t + i * 256];

    float M[128];
    #pragma unroll
    for (int i = 0; i < 128; ++i) M[i] = 0.f;

    // register pipeline of global k loads (bf16, 8 B/lane = full 512 B row/wave)
    const ushort_t* kpl = Kp + lane * 4;
    uint2 g0 = *(const uint2*)(kpl);                       // k[0]
    uint2 ga = *(const uint2*)(kpl + HALFD);               // k[1]
    uint2 gb = *(const uint2*)(kpl + 2 * HALFD);           // k[2]
    *(uint2*)&kw[w][0][lane * 2] = g0;
    __syncthreads();                   // covers bets (and initial kw write order)

    const float invL = 1.0f / 1024.0f;
    // word offset of this thread's 4 rows within the 128-word (256-elem) k row:
    // global row r0 = half*128 + w*32 + rg*4  ->  word r0/2
    const int krw = (half * 128 + w * 32 + rg * 4) >> 1;

    #pragma unroll 2
    for (int s = 0; s < LSEQ - 1; ++s) {
        int cur = s & 1;
        // stage k[s+1] (regs->LDS), advance pipeline (load k[s+3])
        *(uint2*)&kw[w][cur ^ 1][lane * 2] = ga;
        ga = gb;
        int nld = (s + 3 < LSEQ) ? (s + 3) : (LSEQ - 1);
        gb = *(const uint2*)(kpl + (size_t)nld * HALFD);

        // kq: 32 cols of chunk q, conflict-free rotated b128 reads + bf16 unpack
        float kq[32];
        #pragma unroll
        for (int s2 = 0; s2 < 4; ++s2) {
            int sw = (s2 + (q >> 1)) & 3;
            uint4 w4 = *(const uint4*)&kw[w][cur][q * 16 + sw * 4];
            kq[sw * 8 + 0] = __uint_as_float(w4.x << 16);
            kq[sw * 8 + 1] = __uint_as_float(w4.x & 0xffff0000u);
            kq[sw * 8 + 2] = __uint_as_float(w4.y << 16);
            kq[sw * 8 + 3] = __uint_as_float(w4.y & 0xffff0000u);
            kq[sw * 8 + 4] = __uint_as_float(w4.z << 16);
            kq[sw * 8 + 5] = __uint_as_float(w4.z & 0xffff0000u);
            kq[sw * 8 + 6] = __uint_as_float(w4.w << 16);
            kq[sw * 8 + 7] = __uint_as_float(w4.w & 0xffff0000u);
        }
        // k values at this thread's 4 rows
        uint2 kr2 = *(const uint2*)&kw[w][cur][krw];
        float kr0 = __uint_as_float(kr2.x << 16);
        float kr1 = __uint_as_float(kr2.x & 0xffff0000u);
        float kr2f = __uint_as_float(kr2.y << 16);
        float kr3 = __uint_as_float(kr2.y & 0xffff0000u);

        float pd0 = 0.f, pd1 = 0.f, pd2 = 0.f, pd3 = 0.f;
        #pragma unroll
        for (int i = 0; i < 32; ++i) {
            pd0 += M[i] * kq[i];
            pd1 += M[32 + i] * kq[i];
            pd2 += M[64 + i] * kq[i];
            pd3 += M[96 + i] * kq[i];
        }
        pd0 += __shfl_xor(pd0, 1); pd0 += __shfl_xor(pd0, 2); pd0 += __shfl_xor(pd0, 4);
        pd1 += __shfl_xor(pd1, 1); pd1 += __shfl_xor(pd1, 2); pd1 += __shfl_xor(pd1, 4);
        pd2 += __shfl_xor(pd2, 1); pd2 += __shfl_xor(pd2, 2); pd2 += __shfl_xor(pd2, 4);
        pd3 += __shfl_xor(pd3, 1); pd3 += __shfl_xor(pd3, 2); pd3 += __shfl_xor(pd3, 4);

        float rinv = 1.0f / bets[s];
        float a0 = kr0 - pd0 * rinv;
        float a1 = kr1 - pd1 * rinv;
        float a2 = kr2f - pd2 * rinv;
        float a3 = kr3 - pd3 * rinv;
        if (mat) {
            float wt = (float)(s + 1) * invL;
            a0 *= wt; a1 *= wt; a2 *= wt; a3 *= wt;
        }
        #pragma unroll
        for (int i = 0; i < 32; ++i) {
            M[i]      += a0 * kq[i];
            M[32 + i] += a1 * kq[i];
            M[64 + i] += a2 * kq[i];
            M[96 + i] += a3 * kq[i];
        }
    }

    // final matvec with k[L-1] (staged at s = L-2 into buffer 1)
    {
        int cur = (LSEQ - 1) & 1;
        float kq[32];
        #pragma unroll
        for (int s2 = 0; s2 < 4; ++s2) {
            int sw = (s2 + (q >> 1)) & 3;
            uint4 w4 = *(const uint4*)&kw[w][cur][q * 16 + sw * 4];
            kq[sw * 8 + 0] = __uint_as_float(w4.x << 16);
            kq[sw * 8 + 1] = __uint_as_float(w4.x & 0xffff0000u);
            kq[sw * 8 + 2] = __uint_as_float(w4.y << 16);
            kq[sw * 8 + 3] = __uint_as_float(w4.y & 0xffff0000u);
            kq[sw * 8 + 4] = __uint_as_float(w4.z << 16);
            kq[sw * 8 + 5] = __uint_as_float(w4.z & 0xffff0000u);
            kq[sw * 8 + 6] = __uint_as_float(w4.w << 16);
            kq[sw * 8 + 7] = __uint_as_float(w4.w & 0xffff0000u);
        }
        float pd0 = 0.f, pd1 = 0.f, pd2 = 0.f, pd3 = 0.f;
        #pragma unroll
        for (int i = 0; i < 32; ++i) {
            pd0 += M[i] * kq[i];
            pd1 += M[32 + i] * kq[i];
            pd2 += M[64 + i] * kq[i];
            pd3 += M[96 + i] * kq[i];
        }
        pd0 += __shfl_xor(pd0, 1); pd0 += __shfl_xor(pd0, 2); pd0 += __shfl_xor(pd0, 4);
        pd1 += __shfl_xor(pd1, 1); pd1 += __shfl_xor(pd1, 2); pd1 += __shfl_xor(pd1, 4);
        pd2 += __shfl_xor(pd2, 1); pd2 += __shfl_xor(pd2, 2); pd2 += __shfl_xor(pd2, 4);
        pd3 += __shfl_xor(pd3, 1); pd3 += __shfl_xor(pd3, 2); pd3 += __shfl_xor(pd3, 4);
        if (q == 0) {
            float4 o = {pd0, pd1, pd2, pd3};
            int r0 = half * 128 + w * 32 + rg * 4;
            *(float4*)&c[(size_t)b * 512 + mat * 256 + r0] = o;
        }
    }
}

// ---------------- output GEMM: out[64x32000] = c[64x512] @ W[512x32000] + b -------
__global__ __launch_bounds__(256) void out_gemm(
        const float* __restrict__ c, const float* __restrict__ W,
        const float* __restrict__ bias, float* __restrict__ out) {
    __shared__ __align__(16) float cl[32][64];
    int v = blockIdx.x * 256 + threadIdx.x;           // 125*256 = 32000 exactly
    int b0 = blockIdx.y * 32;
    float acc[32];
    #pragma unroll
    for (int b = 0; b < 32; ++b) acc[b] = 0.f;
    for (int kc = 0; kc < 512; kc += 64) {
        __syncthreads();
        for (int i = threadIdx.x; i < 32 * 16; i += 256) {
            int b = i >> 4, qq = (i & 15) * 4;
            *(float4*)&cl[b][qq] = *(const float4*)(c + (size_t)(b0 + b) * 512 + kc + qq);
        }
        __syncthreads();
        for (int kk = 0; kk < 64; ++kk) {
            float wv = W[(size_t)(kc + kk) * V + v];
            #pragma unroll
            for (int b = 0; b < 32; ++b) acc[b] += cl[b][kk] * wv;
        }
    }
    #pragma unroll
    for (int b = 0; b < 32; ++b) out[(size_t)(b0 + b) * V + v] = acc[b] + bias[v];
}

// ---------------- launch ----------------------------------------------------------
extern "C" void kernel_launch(void* const* d_in, const int* in_sizes, int n_in,
                              void* d_out, int out_size, void* d_ws, size_t ws_size,
                              hipStream_t stream) {
    const int*   seq    = (const int*)d_in[0];
    const float* embed  = (const float*)d_in[1];
    const float* ff_w1  = (const float*)d_in[2];
    const float* ff_b1  = (const float*)d_in[3];
    const float* ff_w2  = (const float*)d_in[4];
    const float* ff_b2  = (const float*)d_in[5];
    const float* ln_g   = (const float*)d_in[6];
    const float* ln_b   = (const float*)d_in[7];
    const float* sem_w  = (const float*)d_in[8];
    const float* sem_b  = (const float*)d_in[9];
    const float* epi_w  = (const float*)d_in[10];
    const float* epi_b  = (const float*)d_in[11];
    const float* out_w  = (const float*)d_in[12];
    const float* out_b  = (const float*)d_in[13];
    float* outp = (float*)d_out;

    const int ML = BB * LSEQ;                         // 65536 rows
    // workspace layout (~91.1 MB total — stays under the proven 95.5 MB)
    char* w = (char*)d_ws;
    ushort_t* ks_bf = (ushort_t*)(w + 0);             // 33554432 B (65536x256 bf16)
    ushort_t* ke_bf = (ushort_t*)(w + 33554432);      // 33554432 B
    ushort_t* ebc   = (ushort_t*)(w + 67108864);      //  8388608 B (8192x512 bf16, e/x/h)
    ushort_t* t1c   = (ushort_t*)(w + 75497472);      // 16777216 B (8192x1024 bf16)
    ushort_t* w1t   = (ushort_t*)(w + 92274688);      //  1048576 B
    ushort_t* w2t   = (ushort_t*)(w + 93323264);      //  1048576 B
    ushort_t* semt  = (ushort_t*)(w + 94371840);      //   262144 B
    ushort_t* epit  = (ushort_t*)(w + 94633984);      //   262144 B
    float*    bet_s = (float*)(w + 94896128);         //   262144 B
    float*    bet_e = (float*)(w + 95158272);         //   262144 B
    float*    cbuf  = (float*)(w + 95420416);         //   131072 B  (end 95551488)

    // weight prep (bf16 + transpose)
    transpose_cvt<<<dim3(1024 / 32, 512 / 32), 256, 0, stream>>>(ff_w1, w1t, 512, 1024);
    transpose_cvt<<<dim3(512 / 32, 1024 / 32), 256, 0, stream>>>(ff_w2, w2t, 1024, 512);
    transpose_cvt<<<dim3(256 / 32, 512 / 32), 256, 0, stream>>>(sem_w, semt, 512, 256);
    transpose_cvt<<<dim3(256 / 32, 512 / 32), 256, 0, stream>>>(epi_w, epit, 512, 256);

    // encoder, chunked over rows to bound workspace
    for (int cc = 0; cc < ML / RCH; ++cc) {
        int c0 = cc * RCH;
        gather_kernel<<<RCH, 128, 0, stream>>>(seq + c0, embed, ebc);
        mfma_gemm<1><<<dim3(1024 / 128, RCH / 128), 256, 0, stream>>>(
            ebc, w1t, ff_b1, nullptr, t1c, 1024, 512);
        mfma_gemm<3><<<dim3(512 / 128, RCH / 128), 256, 0, stream>>>(
            t1c, w2t, ff_b2, ebc, ebc, 512, 1024);     // x = ffn + e, in-place
        ln_kernel<<<RCH / 4, 256, 0, stream>>>(ebc, ln_g, ln_b);  // h, in-place
        mfma_gemm<0><<<dim3(256 / 128, RCH / 128), 256, 0, stream>>>(
            ebc, semt, sem_b, nullptr, ks_bf + (size_t)c0 * HALFD, 256, 512);
        mfma_gemm<0><<<dim3(256 / 128, RCH / 128), 256, 0, stream>>>(
            ebc, epit, epi_b, nullptr, ke_bf + (size_t)c0 * HALFD, 256, 512);
    }

    beta_kernel<<<ML / 4, 256, 0, stream>>>(ks_bf, bet_s);
    beta_kernel<<<ML / 4, 256, 0, stream>>>(ke_bf, bet_e);

    scan_kernel<<<256, 256, 0, stream>>>(ks_bf, ke_bf, bet_s, bet_e, cbuf);

    out_gemm<<<dim3(125, 2), 256, 0, stream>>>(cbuf, out_w, out_b, outp);
}

// Round 5
// 1654.308 us; speedup vs baseline: 7.2621x; 7.2621x over previous
//
#include <hip/hip_runtime.h>

typedef unsigned short ushort_t;
typedef unsigned int uint_t;
typedef __attribute__((ext_vector_type(8))) short short8;
typedef __attribute__((ext_vector_type(4))) float f32x4;

static constexpr int V = 32000, H = 512, HALFD = 256, LSEQ = 1024, BB = 64;
static constexpr int RCH = 8192;                 // rows per encoder chunk

__device__ __forceinline__ ushort_t f2bf(float f) {
    uint_t u = __float_as_uint(f);
    u = (u + 0x7FFFu + ((u >> 16) & 1u)) >> 16;
    return (ushort_t)u;
}
__device__ __forceinline__ float bf2f(ushort_t u) {
    return __uint_as_float(((uint_t)u) << 16);
}

// ---------------- weight transpose + fp32->bf16 convert: Wt[n][k] = bf16(W[k][n]) --
__global__ void transpose_cvt(const float* __restrict__ W, ushort_t* __restrict__ Wt,
                              int K, int N) {
    __shared__ float tile[32][33];
    int k0 = blockIdx.y * 32, n0 = blockIdx.x * 32;
    int tx = threadIdx.x & 31, ty = threadIdx.x >> 5;   // 256 threads: ty 0..7
    #pragma unroll
    for (int i = 0; i < 32; i += 8)
        tile[ty + i][tx] = W[(size_t)(k0 + ty + i) * N + n0 + tx];
    __syncthreads();
    #pragma unroll
    for (int i = 0; i < 32; i += 8)
        Wt[(size_t)(n0 + ty + i) * K + k0 + tx] = f2bf(tile[tx][ty + i]);
}

// ---------------- embedding gather (chunk): e bf16 --------------------------------
__global__ void gather_kernel(const int* __restrict__ seq, const float* __restrict__ embed,
                              ushort_t* __restrict__ ebf) {
    int row = blockIdx.x;
    int tok = seq[row];
    float4 v = ((const float4*)(embed + (size_t)tok * H))[threadIdx.x];
    ushort4 o;
    o.x = f2bf(v.x); o.y = f2bf(v.y); o.z = f2bf(v.z); o.w = f2bf(v.w);
    ((ushort4*)(ebf + (size_t)row * H))[threadIdx.x] = o;
}

// ---------------- bf16 MFMA GEMM:  C = f(A[MxK] @ Bt[NxK]^T + bias (+res)) --------
// MODE: 0 = plain, 1 = relu, 3 = +residual(bf16). Output bf16.
template <int MODE>
__global__ __launch_bounds__(256) void mfma_gemm(
        const ushort_t* __restrict__ A, const ushort_t* __restrict__ Bt,
        const float* __restrict__ bias, const ushort_t* __restrict__ res,
        ushort_t* __restrict__ Cout, int N, int K) {
    __shared__ __align__(16) ushort_t Al[128][40];   // pad 32->40 kills 8-way conflicts
    __shared__ __align__(16) ushort_t Bl[128][40];
    int t = threadIdx.x;
    int m0 = blockIdx.y * 128, n0 = blockIdx.x * 128;
    int lane = t & 63, wid = t >> 6;
    int wm = (wid & 1) * 64, wn = (wid >> 1) * 64;
    int lid = lane & 15, quad = lane >> 4;
    int srow = t >> 2, skq = (t & 3) * 8;            // staging: 4 threads/row, 8 bf16 each

    f32x4 acc[4][4];
    #pragma unroll
    for (int i = 0; i < 4; ++i)
        #pragma unroll
        for (int j = 0; j < 4; ++j)
            acc[i][j] = (f32x4){0.f, 0.f, 0.f, 0.f};

    for (int k0 = 0; k0 < K; k0 += 32) {
        short8 a0 = *(const short8*)(A + (size_t)(m0 + srow) * K + k0 + skq);
        short8 a1 = *(const short8*)(A + (size_t)(m0 + 64 + srow) * K + k0 + skq);
        short8 b0 = *(const short8*)(Bt + (size_t)(n0 + srow) * K + k0 + skq);
        short8 b1 = *(const short8*)(Bt + (size_t)(n0 + 64 + srow) * K + k0 + skq);
        __syncthreads();
        *(short8*)&Al[srow][skq]      = a0;
        *(short8*)&Al[64 + srow][skq] = a1;
        *(short8*)&Bl[srow][skq]      = b0;
        *(short8*)&Bl[64 + srow][skq] = b1;
        __syncthreads();
        short8 af[4], bfr[4];
        #pragma unroll
        for (int i = 0; i < 4; ++i)
            af[i] = *(const short8*)&Al[wm + i * 16 + lid][quad * 8];
        #pragma unroll
        for (int i = 0; i < 4; ++i)
            bfr[i] = *(const short8*)&Bl[wn + i * 16 + lid][quad * 8];
        #pragma unroll
        for (int mt = 0; mt < 4; ++mt)
            #pragma unroll
            for (int nt = 0; nt < 4; ++nt)
                acc[mt][nt] = __builtin_amdgcn_mfma_f32_16x16x32_bf16(
                    af[mt], bfr[nt], acc[mt][nt], 0, 0, 0);
    }
    // epilogue: C/D layout col=lane&15, row=quad*4+reg  [m89/m91-verified]
    #pragma unroll
    for (int mt = 0; mt < 4; ++mt) {
        #pragma unroll
        for (int nt = 0; nt < 4; ++nt) {
            #pragma unroll
            for (int rg = 0; rg < 4; ++rg) {
                int row = m0 + wm + mt * 16 + quad * 4 + rg;
                int col = n0 + wn + nt * 16 + lid;
                float v = acc[mt][nt][rg] + bias[col];
                if (MODE == 1) v = fmaxf(v, 0.f);
                if (MODE == 3) v += bf2f(res[(size_t)row * N + col]);
                Cout[(size_t)row * N + col] = f2bf(v);
            }
        }
    }
}

// ---------------- LayerNorm over H=512 (bf16 in-place), one wave per row ----------
__global__ void ln_kernel(ushort_t* X, const float* __restrict__ g,
                          const float* __restrict__ bta) {
    int row = blockIdx.x * 4 + (threadIdx.x >> 6);
    int lane = threadIdx.x & 63;
    ushort_t* xr = X + (size_t)row * H + lane * 8;
    short8 xv = *(short8*)xr;
    float x[8];
    #pragma unroll
    for (int j = 0; j < 8; ++j) x[j] = bf2f((ushort_t)xv[j]);
    float s = 0.f, ss = 0.f;
    #pragma unroll
    for (int j = 0; j < 8; ++j) { s += x[j]; ss += x[j] * x[j]; }
    #pragma unroll
    for (int d = 1; d < 64; d <<= 1) { s += __shfl_xor(s, d); ss += __shfl_xor(ss, d); }
    float mu = s * (1.f / 512.f);
    float var = ss * (1.f / 512.f) - mu * mu;
    float rstd = rsqrtf(var + 1e-5f);
    float4 g0 = *(const float4*)(g + lane * 8);
    float4 g1 = *(const float4*)(g + lane * 8 + 4);
    float4 b0 = *(const float4*)(bta + lane * 8);
    float4 b1 = *(const float4*)(bta + lane * 8 + 4);
    float gg[8] = {g0.x, g0.y, g0.z, g0.w, g1.x, g1.y, g1.z, g1.w};
    float bb[8] = {b0.x, b0.y, b0.z, b0.w, b1.x, b1.y, b1.z, b1.w};
    short8 o;
    #pragma unroll
    for (int j = 0; j < 8; ++j)
        o[j] = (short)f2bf((x[j] - mu) * rstd * gg[j] + bb[j]);
    *(short8*)xr = o;
}

// ---------------- beta[row] = sum(k^2) + 1e-6 (bf16 input), one wave per row ------
__global__ void beta_kernel(const ushort_t* __restrict__ k, float* __restrict__ beta) {
    int row = blockIdx.x * 4 + (threadIdx.x >> 6);
    int lane = threadIdx.x & 63;
    ushort4 a = *(const ushort4*)(k + (size_t)row * HALFD + lane * 4);
    float ax = bf2f(a.x), ay = bf2f(a.y), az = bf2f(a.z), aw = bf2f(a.w);
    float s = ax * ax + ay * ay + az * az + aw * aw;
    #pragma unroll
    for (int d = 1; d < 64; d <<= 1) s += __shfl_xor(s, d);
    if (lane == 0) beta[row] = s + 1e-6f;
}

// ---------------- sequential delta-rule scan --------------------------------------
// grid 256: blk = b*4 + mat*2 + half. 512 threads = 8 waves (2 waves/SIMD).
// Wave w owns global rows [half*128 + w*16, +16); lane: rowgroup rg=lane>>3
// (2 rows), chunk q=lane&7 (32 cols). M[64] = 2 rows x 32 cols in VGPRs.
// Each wave stages its OWN copy of the k row into private LDS (bf16, 512 B),
// register-pipelined (distance 2) -> NO per-step __syncthreads.
// kq LDS reads rotate the WORD ADDRESS by (q>>1) -> conflict-free; destination
// indices are COMPILE-TIME (kq stays in VGPRs — round-3's dynamic-index bug
// forced kq to scratch, 7.5x regression). The per-thread column order is a
// fixed permutation, which leaves dot products / rank-1 updates invariant.
__global__ __launch_bounds__(512) void scan_kernel(
        const ushort_t* __restrict__ ks, const ushort_t* __restrict__ ke,
        const float* __restrict__ beta_s, const float* __restrict__ beta_e,
        float* __restrict__ c) {
    int blk = blockIdx.x;
    int b = blk >> 2, mat = (blk >> 1) & 1, half = blk & 1;
    const ushort_t* Kp = (mat ? ke : ks) + (size_t)b * LSEQ * HALFD;
    const float* Bp = (mat ? beta_e : beta_s) + (size_t)b * LSEQ;
    int t = threadIdx.x;
    int lane = t & 63, w = t >> 6;
    int q = lane & 7, rg = lane >> 3;

    __shared__ uint_t kw[8][2][128];   // per-wave double-buffered k row (bf16 pairs)
    __shared__ float bets[LSEQ];       // all betas, staged once

    // stage betas block-wide (once)
    #pragma unroll
    for (int i = 0; i < 2; ++i) bets[t + i * 512] = Bp[t + i * 512];

    float M[64];
    #pragma unroll
    for (int i = 0; i < 64; ++i) M[i] = 0.f;

    // register pipeline of global k loads (bf16, 8 B/lane = full 512 B row/wave)
    const ushort_t* kpl = Kp + lane * 4;
    uint2 g0 = *(const uint2*)(kpl);                       // k[0]
    uint2 ga = *(const uint2*)(kpl + HALFD);               // k[1]
    uint2 gb = *(const uint2*)(kpl + 2 * HALFD);           // k[2]
    *(uint2*)&kw[w][0][lane * 2] = g0;
    __syncthreads();                   // covers bets (and initial kw write order)

    const float invL = 1.0f / 1024.0f;
    // word offset of this thread's 2 rows within the 128-word (256-elem) k row:
    // global row r0 = half*128 + w*16 + rg*2 (even) -> word r0/2
    const int krw = (half * 128 + w * 16 + rg * 2) >> 1;

    #pragma unroll 2
    for (int s = 0; s < LSEQ - 1; ++s) {
        int cur = s & 1;
        // stage k[s+1] (regs->LDS), advance pipeline (load k[s+3])
        *(uint2*)&kw[w][cur ^ 1][lane * 2] = ga;
        ga = gb;
        int nld = (s + 3 < LSEQ) ? (s + 3) : (LSEQ - 1);
        gb = *(const uint2*)(kpl + (size_t)nld * HALFD);

        // kq: 32 cols of chunk q; rotated LDS ADDRESS (conflict-free), but
        // compile-time DESTINATION indices (kq stays in registers).
        float kq[32];
        #pragma unroll
        for (int s2 = 0; s2 < 4; ++s2) {
            int sw = (s2 + (q >> 1)) & 3;
            uint4 w4 = *(const uint4*)&kw[w][cur][q * 16 + sw * 4];
            kq[s2 * 8 + 0] = __uint_as_float(w4.x << 16);
            kq[s2 * 8 + 1] = __uint_as_float(w4.x & 0xffff0000u);
            kq[s2 * 8 + 2] = __uint_as_float(w4.y << 16);
            kq[s2 * 8 + 3] = __uint_as_float(w4.y & 0xffff0000u);
            kq[s2 * 8 + 4] = __uint_as_float(w4.z << 16);
            kq[s2 * 8 + 5] = __uint_as_float(w4.z & 0xffff0000u);
            kq[s2 * 8 + 6] = __uint_as_float(w4.w << 16);
            kq[s2 * 8 + 7] = __uint_as_float(w4.w & 0xffff0000u);
        }
        // k values at this thread's 2 rows
        uint_t kr2 = kw[w][cur][krw];
        float kr0 = __uint_as_float(kr2 << 16);
        float kr1 = __uint_as_float(kr2 & 0xffff0000u);

        float pd0 = 0.f, pd1 = 0.f;
        #pragma unroll
        for (int i = 0; i < 32; ++i) {
            pd0 += M[i] * kq[i];
            pd1 += M[32 + i] * kq[i];
        }
        pd0 += __shfl_xor(pd0, 1); pd0 += __shfl_xor(pd0, 2); pd0 += __shfl_xor(pd0, 4);
        pd1 += __shfl_xor(pd1, 1); pd1 += __shfl_xor(pd1, 2); pd1 += __shfl_xor(pd1, 4);

        float rinv = 1.0f / bets[s];
        float a0 = kr0 - pd0 * rinv;
        float a1 = kr1 - pd1 * rinv;
        if (mat) {
            float wt = (float)(s + 1) * invL;
            a0 *= wt; a1 *= wt;
        }
        #pragma unroll
        for (int i = 0; i < 32; ++i) {
            M[i]      += a0 * kq[i];
            M[32 + i] += a1 * kq[i];
        }
    }

    // final matvec with k[L-1] (staged at s = L-2 into buffer 1)
    {
        int cur = (LSEQ - 1) & 1;
        float kq[32];
        #pragma unroll
        for (int s2 = 0; s2 < 4; ++s2) {
            int sw = (s2 + (q >> 1)) & 3;
            uint4 w4 = *(const uint4*)&kw[w][cur][q * 16 + sw * 4];
            kq[s2 * 8 + 0] = __uint_as_float(w4.x << 16);
            kq[s2 * 8 + 1] = __uint_as_float(w4.x & 0xffff0000u);
            kq[s2 * 8 + 2] = __uint_as_float(w4.y << 16);
            kq[s2 * 8 + 3] = __uint_as_float(w4.y & 0xffff0000u);
            kq[s2 * 8 + 4] = __uint_as_float(w4.z << 16);
            kq[s2 * 8 + 5] = __uint_as_float(w4.z & 0xffff0000u);
            kq[s2 * 8 + 6] = __uint_as_float(w4.w << 16);
            kq[s2 * 8 + 7] = __uint_as_float(w4.w & 0xffff0000u);
        }
        float pd0 = 0.f, pd1 = 0.f;
        #pragma unroll
        for (int i = 0; i < 32; ++i) {
            pd0 += M[i] * kq[i];
            pd1 += M[32 + i] * kq[i];
        }
        pd0 += __shfl_xor(pd0, 1); pd0 += __shfl_xor(pd0, 2); pd0 += __shfl_xor(pd0, 4);
        pd1 += __shfl_xor(pd1, 1); pd1 += __shfl_xor(pd1, 2); pd1 += __shfl_xor(pd1, 4);
        if (q == 0) {
            int r0 = half * 128 + w * 16 + rg * 2;
            float2 o = {pd0, pd1};
            *(float2*)&c[(size_t)b * 512 + mat * 256 + r0] = o;
        }
    }
}

// ---------------- output GEMM: out[64x32000] = c[64x512] @ W[512x32000] + b -------
__global__ __launch_bounds__(256) void out_gemm(
        const float* __restrict__ c, const float* __restrict__ W,
        const float* __restrict__ bias, float* __restrict__ out) {
    __shared__ __align__(16) float cl[32][64];
    int v = blockIdx.x * 256 + threadIdx.x;           // 125*256 = 32000 exactly
    int b0 = blockIdx.y * 32;
    float acc[32];
    #pragma unroll
    for (int b = 0; b < 32; ++b) acc[b] = 0.f;
    for (int kc = 0; kc < 512; kc += 64) {
        __syncthreads();
        for (int i = threadIdx.x; i < 32 * 16; i += 256) {
            int b = i >> 4, qq = (i & 15) * 4;
            *(float4*)&cl[b][qq] = *(const float4*)(c + (size_t)(b0 + b) * 512 + kc + qq);
        }
        __syncthreads();
        for (int kk = 0; kk < 64; ++kk) {
            float wv = W[(size_t)(kc + kk) * V + v];
            #pragma unroll
            for (int b = 0; b < 32; ++b) acc[b] += cl[b][kk] * wv;
        }
    }
    #pragma unroll
    for (int b = 0; b < 32; ++b) out[(size_t)(b0 + b) * V + v] = acc[b] + bias[v];
}

// ---------------- launch ----------------------------------------------------------
extern "C" void kernel_launch(void* const* d_in, const int* in_sizes, int n_in,
                              void* d_out, int out_size, void* d_ws, size_t ws_size,
                              hipStream_t stream) {
    const int*   seq    = (const int*)d_in[0];
    const float* embed  = (const float*)d_in[1];
    const float* ff_w1  = (const float*)d_in[2];
    const float* ff_b1  = (const float*)d_in[3];
    const float* ff_w2  = (const float*)d_in[4];
    const float* ff_b2  = (const float*)d_in[5];
    const float* ln_g   = (const float*)d_in[6];
    const float* ln_b   = (const float*)d_in[7];
    const float* sem_w  = (const float*)d_in[8];
    const float* sem_b  = (const float*)d_in[9];
    const float* epi_w  = (const float*)d_in[10];
    const float* epi_b  = (const float*)d_in[11];
    const float* out_w  = (const float*)d_in[12];
    const float* out_b  = (const float*)d_in[13];
    float* outp = (float*)d_out;

    const int ML = BB * LSEQ;                         // 65536 rows
    // workspace layout (~91.1 MB total — stays under the proven 95.5 MB)
    char* w = (char*)d_ws;
    ushort_t* ks_bf = (ushort_t*)(w + 0);             // 33554432 B (65536x256 bf16)
    ushort_t* ke_bf = (ushort_t*)(w + 33554432);      // 33554432 B
    ushort_t* ebc   = (ushort_t*)(w + 67108864);      //  8388608 B (8192x512 bf16, e/x/h)
    ushort_t* t1c   = (ushort_t*)(w + 75497472);      // 16777216 B (8192x1024 bf16)
    ushort_t* w1t   = (ushort_t*)(w + 92274688);      //  1048576 B
    ushort_t* w2t   = (ushort_t*)(w + 93323264);      //  1048576 B
    ushort_t* semt  = (ushort_t*)(w + 94371840);      //   262144 B
    ushort_t* epit  = (ushort_t*)(w + 94633984);      //   262144 B
    float*    bet_s = (float*)(w + 94896128);         //   262144 B
    float*    bet_e = (float*)(w + 95158272);         //   262144 B
    float*    cbuf  = (float*)(w + 95420416);         //   131072 B  (end 95551488)

    // weight prep (bf16 + transpose)
    transpose_cvt<<<dim3(1024 / 32, 512 / 32), 256, 0, stream>>>(ff_w1, w1t, 512, 1024);
    transpose_cvt<<<dim3(512 / 32, 1024 / 32), 256, 0, stream>>>(ff_w2, w2t, 1024, 512);
    transpose_cvt<<<dim3(256 / 32, 512 / 32), 256, 0, stream>>>(sem_w, semt, 512, 256);
    transpose_cvt<<<dim3(256 / 32, 512 / 32), 256, 0, stream>>>(epi_w, epit, 512, 256);

    // encoder, chunked over rows to bound workspace
    for (int cc = 0; cc < ML / RCH; ++cc) {
        int c0 = cc * RCH;
        gather_kernel<<<RCH, 128, 0, stream>>>(seq + c0, embed, ebc);
        mfma_gemm<1><<<dim3(1024 / 128, RCH / 128), 256, 0, stream>>>(
            ebc, w1t, ff_b1, nullptr, t1c, 1024, 512);
        mfma_gemm<3><<<dim3(512 / 128, RCH / 128), 256, 0, stream>>>(
            t1c, w2t, ff_b2, ebc, ebc, 512, 1024);     // x = ffn + e, in-place
        ln_kernel<<<RCH / 4, 256, 0, stream>>>(ebc, ln_g, ln_b);  // h, in-place
        mfma_gemm<0><<<dim3(256 / 128, RCH / 128), 256, 0, stream>>>(
            ebc, semt, sem_b, nullptr, ks_bf + (size_t)c0 * HALFD, 256, 512);
        mfma_gemm<0><<<dim3(256 / 128, RCH / 128), 256, 0, stream>>>(
            ebc, epit, epi_b, nullptr, ke_bf + (size_t)c0 * HALFD, 256, 512);
    }

    beta_kernel<<<ML / 4, 256, 0, stream>>>(ks_bf, bet_s);
    beta_kernel<<<ML / 4, 256, 0, stream>>>(ke_bf, bet_e);

    scan_kernel<<<256, 512, 0, stream>>>(ks_bf, ke_bf, bet_s, bet_e, cbuf);

    out_gemm<<<dim3(125, 2), 256, 0, stream>>>(cbuf, out_w, out_b, outp);
}

// Round 6
// 1371.931 us; speedup vs baseline: 8.7568x; 1.2058x over previous
//
#include <hip/hip_runtime.h>

typedef unsigned short ushort_t;
typedef unsigned int uint_t;
typedef __attribute__((ext_vector_type(8))) short short8;
typedef __attribute__((ext_vector_type(4))) float f32x4;

static constexpr int V = 32000, H = 512, HALFD = 256, LSEQ = 1024, BB = 64;

__device__ __forceinline__ ushort_t f2bf(float f) {
    uint_t u = __float_as_uint(f);
    u = (u + 0x7FFFu + ((u >> 16) & 1u)) >> 16;
    return (ushort_t)u;
}
__device__ __forceinline__ float bf2f(ushort_t u) {
    return __uint_as_float(((uint_t)u) << 16);
}
__device__ __forceinline__ float bflo(uint_t u) { return __uint_as_float(u << 16); }
__device__ __forceinline__ float bfhi(uint_t u) { return __uint_as_float(u & 0xffff0000u); }

// ---------------- weight transpose + fp32->bf16 convert: Wt[n][k] = bf16(W[k][n]) --
__global__ void transpose_cvt(const float* __restrict__ W, ushort_t* __restrict__ Wt,
                              int K, int N) {
    __shared__ float tile[32][33];
    int k0 = blockIdx.y * 32, n0 = blockIdx.x * 32;
    int tx = threadIdx.x & 31, ty = threadIdx.x >> 5;   // 256 threads: ty 0..7
    #pragma unroll
    for (int i = 0; i < 32; i += 8)
        tile[ty + i][tx] = W[(size_t)(k0 + ty + i) * N + n0 + tx];
    __syncthreads();
    #pragma unroll
    for (int i = 0; i < 32; i += 8)
        Wt[(size_t)(n0 + ty + i) * K + k0 + tx] = f2bf(tile[tx][ty + i]);
}

// ======================= GEMM 1: t1 = relu(gather(embed,seq) @ w1 + b1) ===========
// A is gathered on the fly: row r -> embed[seq[r]] (fp32 -> bf16 pack in staging).
__global__ __launch_bounds__(256) void gemm_ffn1(
        const int* __restrict__ seqp, const float* __restrict__ embed,
        const ushort_t* __restrict__ Bt, const float* __restrict__ bias,
        ushort_t* __restrict__ Cout, int N, int K) {
    __shared__ __align__(16) ushort_t Al[128][40];
    __shared__ __align__(16) ushort_t Bl[128][40];
    int t = threadIdx.x;
    int m0 = blockIdx.y * 128, n0 = blockIdx.x * 128;
    int lane = t & 63, wid = t >> 6;
    int wm = (wid & 1) * 64, wn = (wid >> 1) * 64;
    int lid = lane & 15, quad = lane >> 4;
    int srow = t >> 2, skq = (t & 3) * 8;

    int tok0 = seqp[m0 + srow];
    int tok1 = seqp[m0 + 64 + srow];
    const float* e0 = embed + (size_t)tok0 * H + skq;
    const float* e1 = embed + (size_t)tok1 * H + skq;

    f32x4 acc[4][4];
    #pragma unroll
    for (int i = 0; i < 4; ++i)
        #pragma unroll
        for (int j = 0; j < 4; ++j)
            acc[i][j] = (f32x4){0.f, 0.f, 0.f, 0.f};

    for (int k0 = 0; k0 < K; k0 += 32) {
        float4 ea0 = *(const float4*)(e0 + k0);
        float4 eb0 = *(const float4*)(e0 + k0 + 4);
        float4 ea1 = *(const float4*)(e1 + k0);
        float4 eb1 = *(const float4*)(e1 + k0 + 4);
        short8 b0 = *(const short8*)(Bt + (size_t)(n0 + srow) * K + k0 + skq);
        short8 b1 = *(const short8*)(Bt + (size_t)(n0 + 64 + srow) * K + k0 + skq);
        short8 s0, s1;
        s0[0] = (short)f2bf(ea0.x); s0[1] = (short)f2bf(ea0.y);
        s0[2] = (short)f2bf(ea0.z); s0[3] = (short)f2bf(ea0.w);
        s0[4] = (short)f2bf(eb0.x); s0[5] = (short)f2bf(eb0.y);
        s0[6] = (short)f2bf(eb0.z); s0[7] = (short)f2bf(eb0.w);
        s1[0] = (short)f2bf(ea1.x); s1[1] = (short)f2bf(ea1.y);
        s1[2] = (short)f2bf(ea1.z); s1[3] = (short)f2bf(ea1.w);
        s1[4] = (short)f2bf(eb1.x); s1[5] = (short)f2bf(eb1.y);
        s1[6] = (short)f2bf(eb1.z); s1[7] = (short)f2bf(eb1.w);
        __syncthreads();
        *(short8*)&Al[srow][skq]      = s0;
        *(short8*)&Al[64 + srow][skq] = s1;
        *(short8*)&Bl[srow][skq]      = b0;
        *(short8*)&Bl[64 + srow][skq] = b1;
        __syncthreads();
        short8 af[4], bfr[4];
        #pragma unroll
        for (int i = 0; i < 4; ++i)
            af[i] = *(const short8*)&Al[wm + i * 16 + lid][quad * 8];
        #pragma unroll
        for (int i = 0; i < 4; ++i)
            bfr[i] = *(const short8*)&Bl[wn + i * 16 + lid][quad * 8];
        #pragma unroll
        for (int mt = 0; mt < 4; ++mt)
            #pragma unroll
            for (int nt = 0; nt < 4; ++nt)
                acc[mt][nt] = __builtin_amdgcn_mfma_f32_16x16x32_bf16(
                    af[mt], bfr[nt], acc[mt][nt], 0, 0, 0);
    }
    #pragma unroll
    for (int mt = 0; mt < 4; ++mt)
        #pragma unroll
        for (int nt = 0; nt < 4; ++nt)
            #pragma unroll
            for (int rg = 0; rg < 4; ++rg) {
                int row = m0 + wm + mt * 16 + quad * 4 + rg;
                int col = n0 + wn + nt * 16 + lid;
                float v = fmaxf(acc[mt][nt][rg] + bias[col], 0.f);
                Cout[(size_t)row * N + col] = f2bf(v);
            }
}

// ======================= GEMM 2: x = t1 @ w2 + b2 + gather(embed,seq) =============
__global__ __launch_bounds__(256) void gemm_ffn2(
        const ushort_t* __restrict__ A, const ushort_t* __restrict__ Bt,
        const float* __restrict__ bias, const int* __restrict__ seqp,
        const float* __restrict__ embed, ushort_t* __restrict__ Cout,
        int N, int K) {
    __shared__ __align__(16) ushort_t Al[128][40];
    __shared__ __align__(16) ushort_t Bl[128][40];
    int t = threadIdx.x;
    int m0 = blockIdx.y * 128, n0 = blockIdx.x * 128;
    int lane = t & 63, wid = t >> 6;
    int wm = (wid & 1) * 64, wn = (wid >> 1) * 64;
    int lid = lane & 15, quad = lane >> 4;
    int srow = t >> 2, skq = (t & 3) * 8;

    f32x4 acc[4][4];
    #pragma unroll
    for (int i = 0; i < 4; ++i)
        #pragma unroll
        for (int j = 0; j < 4; ++j)
            acc[i][j] = (f32x4){0.f, 0.f, 0.f, 0.f};

    for (int k0 = 0; k0 < K; k0 += 32) {
        short8 a0 = *(const short8*)(A + (size_t)(m0 + srow) * K + k0 + skq);
        short8 a1 = *(const short8*)(A + (size_t)(m0 + 64 + srow) * K + k0 + skq);
        short8 b0 = *(const short8*)(Bt + (size_t)(n0 + srow) * K + k0 + skq);
        short8 b1 = *(const short8*)(Bt + (size_t)(n0 + 64 + srow) * K + k0 + skq);
        __syncthreads();
        *(short8*)&Al[srow][skq]      = a0;
        *(short8*)&Al[64 + srow][skq] = a1;
        *(short8*)&Bl[srow][skq]      = b0;
        *(short8*)&Bl[64 + srow][skq] = b1;
        __syncthreads();
        short8 af[4], bfr[4];
        #pragma unroll
        for (int i = 0; i < 4; ++i)
            af[i] = *(const short8*)&Al[wm + i * 16 + lid][quad * 8];
        #pragma unroll
        for (int i = 0; i < 4; ++i)
            bfr[i] = *(const short8*)&Bl[wn + i * 16 + lid][quad * 8];
        #pragma unroll
        for (int mt = 0; mt < 4; ++mt)
            #pragma unroll
            for (int nt = 0; nt < 4; ++nt)
                acc[mt][nt] = __builtin_amdgcn_mfma_f32_16x16x32_bf16(
                    af[mt], bfr[nt], acc[mt][nt], 0, 0, 0);
    }
    #pragma unroll
    for (int mt = 0; mt < 4; ++mt)
        #pragma unroll
        for (int rg = 0; rg < 4; ++rg) {
            int row = m0 + wm + mt * 16 + quad * 4 + rg;
            int tok = seqp[row];
            const float* erow = embed + (size_t)tok * H;
            #pragma unroll
            for (int nt = 0; nt < 4; ++nt) {
                int col = n0 + wn + nt * 16 + lid;
                float v = acc[mt][nt][rg] + bias[col] + erow[col];
                Cout[(size_t)row * N + col] = f2bf(v);
            }
        }
}

// ====== fused projections: [ks|ke] = h @ [sem_w|epi_w] + b  (Bt rows concat) ======
__global__ __launch_bounds__(256) void gemm_proj(
        const ushort_t* __restrict__ A, const ushort_t* __restrict__ Bt,
        const float* __restrict__ biasS, const float* __restrict__ biasE,
        ushort_t* __restrict__ outS, ushort_t* __restrict__ outE, int K) {
    __shared__ __align__(16) ushort_t Al[128][40];
    __shared__ __align__(16) ushort_t Bl[128][40];
    int t = threadIdx.x;
    int m0 = blockIdx.y * 128, n0 = blockIdx.x * 128;   // n0 in 0..384
    int lane = t & 63, wid = t >> 6;
    int wm = (wid & 1) * 64, wn = (wid >> 1) * 64;
    int lid = lane & 15, quad = lane >> 4;
    int srow = t >> 2, skq = (t & 3) * 8;

    f32x4 acc[4][4];
    #pragma unroll
    for (int i = 0; i < 4; ++i)
        #pragma unroll
        for (int j = 0; j < 4; ++j)
            acc[i][j] = (f32x4){0.f, 0.f, 0.f, 0.f};

    for (int k0 = 0; k0 < K; k0 += 32) {
        short8 a0 = *(const short8*)(A + (size_t)(m0 + srow) * K + k0 + skq);
        short8 a1 = *(const short8*)(A + (size_t)(m0 + 64 + srow) * K + k0 + skq);
        short8 b0 = *(const short8*)(Bt + (size_t)(n0 + srow) * K + k0 + skq);
        short8 b1 = *(const short8*)(Bt + (size_t)(n0 + 64 + srow) * K + k0 + skq);
        __syncthreads();
        *(short8*)&Al[srow][skq]      = a0;
        *(short8*)&Al[64 + srow][skq] = a1;
        *(short8*)&Bl[srow][skq]      = b0;
        *(short8*)&Bl[64 + srow][skq] = b1;
        __syncthreads();
        short8 af[4], bfr[4];
        #pragma unroll
        for (int i = 0; i < 4; ++i)
            af[i] = *(const short8*)&Al[wm + i * 16 + lid][quad * 8];
        #pragma unroll
        for (int i = 0; i < 4; ++i)
            bfr[i] = *(const short8*)&Bl[wn + i * 16 + lid][quad * 8];
        #pragma unroll
        for (int mt = 0; mt < 4; ++mt)
            #pragma unroll
            for (int nt = 0; nt < 4; ++nt)
                acc[mt][nt] = __builtin_amdgcn_mfma_f32_16x16x32_bf16(
                    af[mt], bfr[nt], acc[mt][nt], 0, 0, 0);
    }
    #pragma unroll
    for (int mt = 0; mt < 4; ++mt)
        #pragma unroll
        for (int nt = 0; nt < 4; ++nt)
            #pragma unroll
            for (int rg = 0; rg < 4; ++rg) {
                int row = m0 + wm + mt * 16 + quad * 4 + rg;
                int col = n0 + wn + nt * 16 + lid;   // wave-uniform half selection
                if (col < 256)
                    outS[(size_t)row * HALFD + col] = f2bf(acc[mt][nt][rg] + biasS[col]);
                else
                    outE[(size_t)row * HALFD + col - 256] =
                        f2bf(acc[mt][nt][rg] + biasE[col - 256]);
            }
}

// ---------------- LayerNorm over H=512 (bf16 in-place), one wave per row ----------
__global__ void ln_kernel(ushort_t* X, const float* __restrict__ g,
                          const float* __restrict__ bta) {
    int row = blockIdx.x * 4 + (threadIdx.x >> 6);
    int lane = threadIdx.x & 63;
    ushort_t* xr = X + (size_t)row * H + lane * 8;
    short8 xv = *(short8*)xr;
    float x[8];
    #pragma unroll
    for (int j = 0; j < 8; ++j) x[j] = bf2f((ushort_t)xv[j]);
    float s = 0.f, ss = 0.f;
    #pragma unroll
    for (int j = 0; j < 8; ++j) { s += x[j]; ss += x[j] * x[j]; }
    #pragma unroll
    for (int d = 1; d < 64; d <<= 1) { s += __shfl_xor(s, d); ss += __shfl_xor(ss, d); }
    float mu = s * (1.f / 512.f);
    float var = ss * (1.f / 512.f) - mu * mu;
    float rstd = rsqrtf(var + 1e-5f);
    float4 g0 = *(const float4*)(g + lane * 8);
    float4 g1 = *(const float4*)(g + lane * 8 + 4);
    float4 b0 = *(const float4*)(bta + lane * 8);
    float4 b1 = *(const float4*)(bta + lane * 8 + 4);
    float gg[8] = {g0.x, g0.y, g0.z, g0.w, g1.x, g1.y, g1.z, g1.w};
    float bb[8] = {b0.x, b0.y, b0.z, b0.w, b1.x, b1.y, b1.z, b1.w};
    short8 o;
    #pragma unroll
    for (int j = 0; j < 8; ++j)
        o[j] = (short)f2bf((x[j] - mu) * rstd * gg[j] + bb[j]);
    *(short8*)xr = o;
}

// ---------------- beta[row] = sum(k^2) + 1e-6 (bf16 input), one wave per row ------
__global__ void beta_kernel(const ushort_t* __restrict__ k, float* __restrict__ beta) {
    int row = blockIdx.x * 4 + (threadIdx.x >> 6);
    int lane = threadIdx.x & 63;
    ushort4 a = *(const ushort4*)(k + (size_t)row * HALFD + lane * 4);
    float ax = bf2f(a.x), ay = bf2f(a.y), az = bf2f(a.z), aw = bf2f(a.w);
    float s = ax * ax + ay * ay + az * az + aw * aw;
    #pragma unroll
    for (int d = 1; d < 64; d <<= 1) s += __shfl_xor(s, d);
    if (lane == 0) beta[row] = s + 1e-6f;
}

// ---------------- sequential delta-rule scan --------------------------------------
// grid 256: blk = b*4 + mat*2 + half. 512 threads = 8 waves (2 waves/SIMD).
// Wave w owns global rows [half*128 + w*16, +16); lane: rowgroup rg=lane>>3
// (2 rows), chunk q=lane&7 (32 cols). M[64] = 2 rows x 32 cols in VGPRs.
// k rows staged into per-wave private LDS as FP32 (converted once at staging;
// no per-step unpack). Double-buffered, register-pipelined -> no per-step
// __syncthreads. kq reads rotate the LDS ADDRESS by q (conflict-free across
// the 8 chunk groups, broadcast across rowgroups); destination indices are
// compile-time (kq stays in VGPRs — round-4 lesson).
__global__ __launch_bounds__(512) void scan_kernel(
        const ushort_t* __restrict__ ks, const ushort_t* __restrict__ ke,
        const float* __restrict__ beta_s, const float* __restrict__ beta_e,
        float* __restrict__ c) {
    int blk = blockIdx.x;
    int b = blk >> 2, mat = (blk >> 1) & 1, half = blk & 1;
    const ushort_t* Kp = (mat ? ke : ks) + (size_t)b * LSEQ * HALFD;
    const float* Bp = (mat ? beta_e : beta_s) + (size_t)b * LSEQ;
    int t = threadIdx.x;
    int lane = t & 63, w = t >> 6;
    int q = lane & 7, rg = lane >> 3;

    __shared__ float kw[8][2][256];    // per-wave double-buffered fp32 k row (16 KB)
    __shared__ float bets[LSEQ];       // all betas (4 KB)

    #pragma unroll
    for (int i = 0; i < 2; ++i) bets[t + i * 512] = Bp[t + i * 512];

    float M[64];
    #pragma unroll
    for (int i = 0; i < 64; ++i) M[i] = 0.f;

    // register pipeline of global k loads (4 bf16/lane = full 512 B row/wave)
    const ushort_t* kpl = Kp + lane * 4;
    uint2 g0 = *(const uint2*)(kpl);                       // k[0]
    uint2 ga = *(const uint2*)(kpl + HALFD);               // k[1]
    uint2 gb = *(const uint2*)(kpl + 2 * HALFD);           // k[2]
    {
        float4 f = {bflo(g0.x), bfhi(g0.x), bflo(g0.y), bfhi(g0.y)};
        *(float4*)&kw[w][0][lane * 4] = f;
    }
    __syncthreads();                   // covers bets + initial staging

    const float invL = 1.0f / 1024.0f;
    // float index of this thread's 2 rows within the 256-float k row
    const int r0 = half * 128 + w * 16 + rg * 2;

    #pragma unroll 2
    for (int s = 0; s < LSEQ - 1; ++s) {
        int cur = s & 1;
        // stage k[s+1] (regs->LDS, cvt to fp32), advance pipeline (load k[s+3])
        {
            float4 f = {bflo(ga.x), bfhi(ga.x), bflo(ga.y), bfhi(ga.y)};
            *(float4*)&kw[w][cur ^ 1][lane * 4] = f;
        }
        ga = gb;
        int nld = (s + 3 < LSEQ) ? (s + 3) : (LSEQ - 1);
        gb = *(const uint2*)(kpl + (size_t)nld * HALFD);

        // kq: 32 cols of chunk q; rotated address, compile-time destinations
        float kq[32];
        #pragma unroll
        for (int j = 0; j < 8; ++j) {
            int sw = (j + q) & 7;
            float4 v = *(const float4*)&kw[w][cur][q * 32 + sw * 4];
            kq[j * 4 + 0] = v.x; kq[j * 4 + 1] = v.y;
            kq[j * 4 + 2] = v.z; kq[j * 4 + 3] = v.w;
        }
        float2 krv = *(const float2*)&kw[w][cur][r0];

        float pd0 = 0.f, pd1 = 0.f;
        #pragma unroll
        for (int i = 0; i < 32; ++i) {
            pd0 += M[i] * kq[i];
            pd1 += M[32 + i] * kq[i];
        }
        pd0 += __shfl_xor(pd0, 1); pd0 += __shfl_xor(pd0, 2); pd0 += __shfl_xor(pd0, 4);
        pd1 += __shfl_xor(pd1, 1); pd1 += __shfl_xor(pd1, 2); pd1 += __shfl_xor(pd1, 4);

        float rinv = 1.0f / bets[s];
        float a0 = krv.x - pd0 * rinv;
        float a1 = krv.y - pd1 * rinv;
        if (mat) {
            float wt = (float)(s + 1) * invL;
            a0 *= wt; a1 *= wt;
        }
        #pragma unroll
        for (int i = 0; i < 32; ++i) {
            M[i]      += a0 * kq[i];
            M[32 + i] += a1 * kq[i];
        }
    }

    // final matvec with k[L-1] (staged at s = L-2 into buffer 1)
    {
        int cur = (LSEQ - 1) & 1;
        float kq[32];
        #pragma unroll
        for (int j = 0; j < 8; ++j) {
            int sw = (j + q) & 7;
            float4 v = *(const float4*)&kw[w][cur][q * 32 + sw * 4];
            kq[j * 4 + 0] = v.x; kq[j * 4 + 1] = v.y;
            kq[j * 4 + 2] = v.z; kq[j * 4 + 3] = v.w;
        }
        float pd0 = 0.f, pd1 = 0.f;
        #pragma unroll
        for (int i = 0; i < 32; ++i) {
            pd0 += M[i] * kq[i];
            pd1 += M[32 + i] * kq[i];
        }
        pd0 += __shfl_xor(pd0, 1); pd0 += __shfl_xor(pd0, 2); pd0 += __shfl_xor(pd0, 4);
        pd1 += __shfl_xor(pd1, 1); pd1 += __shfl_xor(pd1, 2); pd1 += __shfl_xor(pd1, 4);
        if (q == 0) {
            float2 o = {pd0, pd1};
            *(float2*)&c[(size_t)b * 512 + mat * 256 + r0] = o;
        }
    }
}

// ---------------- output GEMM: out[64x32000] = c[64x512] @ W[512x32000] + b -------
__global__ __launch_bounds__(256) void out_gemm(
        const float* __restrict__ c, const float* __restrict__ W,
        const float* __restrict__ bias, float* __restrict__ out) {
    __shared__ __align__(16) float cl[32][64];
    int v = blockIdx.x * 256 + threadIdx.x;           // 125*256 = 32000 exactly
    int b0 = blockIdx.y * 32;
    float acc[32];
    #pragma unroll
    for (int b = 0; b < 32; ++b) acc[b] = 0.f;
    for (int kc = 0; kc < 512; kc += 64) {
        __syncthreads();
        for (int i = threadIdx.x; i < 32 * 16; i += 256) {
            int b = i >> 4, qq = (i & 15) * 4;
            *(float4*)&cl[b][qq] = *(const float4*)(c + (size_t)(b0 + b) * 512 + kc + qq);
        }
        __syncthreads();
        for (int kk = 0; kk < 64; ++kk) {
            float wv = W[(size_t)(kc + kk) * V + v];
            #pragma unroll
            for (int b = 0; b < 32; ++b) acc[b] += cl[b][kk] * wv;
        }
    }
    #pragma unroll
    for (int b = 0; b < 32; ++b) out[(size_t)(b0 + b) * V + v] = acc[b] + bias[v];
}

// ---------------- launch ----------------------------------------------------------
extern "C" void kernel_launch(void* const* d_in, const int* in_sizes, int n_in,
                              void* d_out, int out_size, void* d_ws, size_t ws_size,
                              hipStream_t stream) {
    const int*   seq    = (const int*)d_in[0];
    const float* embed  = (const float*)d_in[1];
    const float* ff_w1  = (const float*)d_in[2];
    const float* ff_b1  = (const float*)d_in[3];
    const float* ff_w2  = (const float*)d_in[4];
    const float* ff_b2  = (const float*)d_in[5];
    const float* ln_g   = (const float*)d_in[6];
    const float* ln_b   = (const float*)d_in[7];
    const float* sem_w  = (const float*)d_in[8];
    const float* sem_b  = (const float*)d_in[9];
    const float* epi_w  = (const float*)d_in[10];
    const float* epi_b  = (const float*)d_in[11];
    const float* out_w  = (const float*)d_in[12];
    const float* out_b  = (const float*)d_in[13];
    float* outp = (float*)d_out;

    const int ML = BB * LSEQ;                         // 65536 rows
    // adaptive chunk: fixed = 70,385,664 B; chunk = RCH*3072 B.
    int RCH;
    if      (ws_size >= 271712256ull) RCH = 65536;    // 1 chunk
    else if (ws_size >= 120717312ull) RCH = 16384;    // 4 chunks
    else                              RCH = 8192;     // 8 chunks (95,551,488 proven)

    char* w = (char*)d_ws;
    size_t off = 0;
    ushort_t* ks_bf = (ushort_t*)(w + off); off += 33554432;          // 65536x256 bf16
    ushort_t* ke_bf = (ushort_t*)(w + off); off += 33554432;
    ushort_t* ebc   = (ushort_t*)(w + off); off += (size_t)RCH * 512 * 2;   // x/h chunk
    ushort_t* t1c   = (ushort_t*)(w + off); off += (size_t)RCH * 1024 * 2;  // relu chunk
    ushort_t* w1t   = (ushort_t*)(w + off); off += 1048576;
    ushort_t* w2t   = (ushort_t*)(w + off); off += 1048576;
    ushort_t* semt  = (ushort_t*)(w + off); off += 262144;            // semt|epit adjacent
    ushort_t* epit  = (ushort_t*)(w + off); off += 262144;
    float*    bet_s = (float*)(w + off);    off += 262144;
    float*    bet_e = (float*)(w + off);    off += 262144;
    float*    cbuf  = (float*)(w + off);    off += 131072;

    // weight prep (bf16 + transpose)
    transpose_cvt<<<dim3(1024 / 32, 512 / 32), 256, 0, stream>>>(ff_w1, w1t, 512, 1024);
    transpose_cvt<<<dim3(512 / 32, 1024 / 32), 256, 0, stream>>>(ff_w2, w2t, 1024, 512);
    transpose_cvt<<<dim3(256 / 32, 512 / 32), 256, 0, stream>>>(sem_w, semt, 512, 256);
    transpose_cvt<<<dim3(256 / 32, 512 / 32), 256, 0, stream>>>(epi_w, epit, 512, 256);

    // encoder, chunked over rows to bound workspace
    for (int cc = 0; cc < ML / RCH; ++cc) {
        int c0 = cc * RCH;
        gemm_ffn1<<<dim3(1024 / 128, RCH / 128), 256, 0, stream>>>(
            seq + c0, embed, w1t, ff_b1, t1c, 1024, 512);
        gemm_ffn2<<<dim3(512 / 128, RCH / 128), 256, 0, stream>>>(
            t1c, w2t, ff_b2, seq + c0, embed, ebc, 512, 1024);
        ln_kernel<<<RCH / 4, 256, 0, stream>>>(ebc, ln_g, ln_b);  // h, in-place
        gemm_proj<<<dim3(512 / 128, RCH / 128), 256, 0, stream>>>(
            ebc, semt, sem_b, epi_b,
            ks_bf + (size_t)c0 * HALFD, ke_bf + (size_t)c0 * HALFD, 512);
    }

    beta_kernel<<<ML / 4, 256, 0, stream>>>(ks_bf, bet_s);
    beta_kernel<<<ML / 4, 256, 0, stream>>>(ke_bf, bet_e);

    scan_kernel<<<256, 512, 0, stream>>>(ks_bf, ke_bf, bet_s, bet_e, cbuf);

    out_gemm<<<dim3(125, 2), 256, 0, stream>>>(cbuf, out_w, out_b, outp);
}